// Round 1
// baseline (171.041 us; speedup 1.0000x reference)
//
#include <hip/hip_runtime.h>
#include <cstdint>
#include <cstddef>

#define B_ 16
#define S_ 2048
#define D_ 128
#define M_ 32            // q-rows per block
#define NW 8             // waves per block
#define CPW (S_ / NW)    // score columns per wave = 256
#define PSTR 2056        // p_lds row stride in halves (4112 B -> 2-way max on b128)

typedef float  f32x4 __attribute__((ext_vector_type(4)));
typedef _Float16 f16x8 __attribute__((ext_vector_type(8)));
typedef _Float16 f16x4 __attribute__((ext_vector_type(4)));

// log2(e) / sqrt(128)
#define SCALE_ 0.12751743f

// ---------------- pre-pass: f32 -> f16 convert ----------------
__global__ void cvt_f16_kernel(const float* __restrict__ in,
                               _Float16* __restrict__ out, int n4) {
  for (int i = blockIdx.x * blockDim.x + threadIdx.x; i < n4;
       i += gridDim.x * blockDim.x) {
    f32x4 v = ((const f32x4*)in)[i];
    f16x4 h;
    for (int j = 0; j < 4; ++j) h[j] = (_Float16)v[j];
    ((f16x4*)out)[i] = h;
  }
}

// ---------------- pre-pass: V [b][k][d] -> Vt [b][d][k] (f16) ----------------
__global__ void trans_v_kernel(const float* __restrict__ v,
                               _Float16* __restrict__ vt) {
  __shared__ _Float16 t[32][33];
  int blk = blockIdx.x;
  int dt = blk & 3;          // 4 d-tiles of 32
  int kt = (blk >> 2) & 63;  // 64 k-tiles of 32
  int b  = blk >> 8;         // 16 batches
  int tx = threadIdx.x & 31, ty = threadIdx.x >> 5;  // 32 x 8
  int k0 = kt * 32, d0 = dt * 32;
  for (int i = 0; i < 4; ++i) {
    int kk = ty + i * 8;
    t[kk][tx] = (_Float16)v[((size_t)b * S_ + k0 + kk) * D_ + d0 + tx];
  }
  __syncthreads();
  for (int i = 0; i < 4; ++i) {
    int dd = ty + i * 8;
    vt[((size_t)b * D_ + d0 + dd) * S_ + k0 + tx] = t[tx][dd];
  }
}

// ---------------- fused attention ----------------
template <bool WS>
__global__ __launch_bounds__(512, 2)
void attn_fused(const float* __restrict__ Qf, const float* __restrict__ Kf,
                const float* __restrict__ Vf,
                const _Float16* __restrict__ Qh, const _Float16* __restrict__ Kh,
                const _Float16* __restrict__ Vt,
                float* __restrict__ outO, float* __restrict__ outA) {
  __shared__ _Float16 p_lds[M_][PSTR];   // unnormalized exp scores, fp16
  __shared__ float wsum[NW][M_];
  __shared__ float inv_l[M_];

  const int tid  = threadIdx.x;
  const int w    = tid >> 6;
  const int lane = tid & 63;
  const int lg   = lane >> 4;   // 0..3
  const int lr   = lane & 15;   // 0..15
  const int blk  = blockIdx.x;
  const int b    = blk & 15;    // batch -> XCD = b&7 (2 batches per XCD L2)
  const int qt   = blk >> 4;    // 0..63
  const int q0   = qt * M_;

  // ---- Q fragments: A[m=lr][k = 32*kk + 8*lg + j], two 16-row halves ----
  f16x8 aq[2][4];
  for (int h = 0; h < 2; ++h) {
    const int row = q0 + h * 16 + lr;
    for (int kk = 0; kk < 4; ++kk) {
      const size_t off = ((size_t)b * S_ + row) * D_ + kk * 32 + lg * 8;
      if constexpr (WS) {
        aq[h][kk] = *(const f16x8*)(Qh + off);
      } else {
        const float* p = Qf + off;
        f32x4 v0 = *(const f32x4*)p, v1 = *(const f32x4*)(p + 4);
        f16x8 a;
        for (int j = 0; j < 4; ++j) { a[j] = (_Float16)v0[j]; a[4 + j] = (_Float16)v1[j]; }
        aq[h][kk] = a;
      }
    }
  }

  // ---- Phase 1: S = QK^T / temper, P = exp(S), row partial sums ----
  float psum[2][4] = {};
  for (int ct = 0; ct < CPW / 16; ++ct) {
    const int col0 = w * CPW + ct * 16;
    f32x4 acc0 = {0.f, 0.f, 0.f, 0.f}, acc1 = {0.f, 0.f, 0.f, 0.f};
    for (int kk = 0; kk < 4; ++kk) {
      // B[k = 32*kk + 8*lg + j][n = col0 + lr] = K[col0+lr][...]
      f16x8 bk;
      const size_t off = ((size_t)b * S_ + col0 + lr) * D_ + kk * 32 + lg * 8;
      if constexpr (WS) {
        bk = *(const f16x8*)(Kh + off);
      } else {
        const float* p = Kf + off;
        f32x4 v0 = *(const f32x4*)p, v1 = *(const f32x4*)(p + 4);
        for (int j = 0; j < 4; ++j) { bk[j] = (_Float16)v0[j]; bk[4 + j] = (_Float16)v1[j]; }
      }
      acc0 = __builtin_amdgcn_mfma_f32_16x16x32_f16(aq[0][kk], bk, acc0, 0, 0, 0);
      acc1 = __builtin_amdgcn_mfma_f32_16x16x32_f16(aq[1][kk], bk, acc1, 0, 0, 0);
    }
    // D layout: col = lane&15, row = 4*(lane>>4) + r
    for (int r = 0; r < 4; ++r) {
      float p0 = exp2f(acc0[r] * SCALE_);
      float p1 = exp2f(acc1[r] * SCALE_);
      psum[0][r] += p0;
      psum[1][r] += p1;
      p_lds[lg * 4 + r][col0 + lr]      = (_Float16)p0;
      p_lds[16 + lg * 4 + r][col0 + lr] = (_Float16)p1;
    }
  }

  // deterministic row-sum reduction: shfl within 16-lane groups, then fixed-order
  for (int h = 0; h < 2; ++h)
    for (int r = 0; r < 4; ++r) {
      float s = psum[h][r];
      s += __shfl_xor(s, 1);
      s += __shfl_xor(s, 2);
      s += __shfl_xor(s, 4);
      s += __shfl_xor(s, 8);
      if (lr == 0) wsum[w][h * 16 + lg * 4 + r] = s;
    }
  __syncthreads();
  if (tid < M_) {
    float s = 0.f;
    for (int i = 0; i < NW; ++i) s += wsum[i][tid];
    inv_l[tid] = 1.0f / s;
  }
  __syncthreads();

  // ---- Phase 2+3 fused: O = P·V (MFMA) interleaved with attn row writes ----
  const int d0v = w * 16;
  f32x4 o0 = {0.f, 0.f, 0.f, 0.f}, o1 = {0.f, 0.f, 0.f, 0.f};

  for (int kb = 0; kb < S_ / 32; ++kb) {  // 64 iterations
    const int k0 = kb * 32;
    // B[k = k0 + 8*lg + j][n = d0v + lr] = V[k][d] = Vt[d][k]
    f16x8 bv;
    if constexpr (WS) {
      bv = *(const f16x8*)(Vt + ((size_t)b * D_ + d0v + lr) * S_ + k0 + lg * 8);
    } else {
      const float* vp = Vf + ((size_t)b * S_ + k0 + lg * 8) * D_ + d0v + lr;
      for (int j = 0; j < 8; ++j) bv[j] = (_Float16)vp[(size_t)j * D_];
    }
    // A[m = lr][k = k0 + 8*lg + j] from LDS (contiguous 16B)
    f16x8 ap0 = *(const f16x8*)(&p_lds[lr][k0 + lg * 8]);
    f16x8 ap1 = *(const f16x8*)(&p_lds[16 + lr][k0 + lg * 8]);
    o0 = __builtin_amdgcn_mfma_f32_16x16x32_f16(ap0, bv, o0, 0, 0, 0);
    o1 = __builtin_amdgcn_mfma_f32_16x16x32_f16(ap1, bv, o1, 0, 0, 0);

    // interleaved attn store: every 2nd iter, one full row-slice, 1KB contiguous
    if (kb & 1) {
      const int row = kb >> 1;  // 0..31
      const int c0  = w * CPW + lane * 4;
      f16x4 pv = *(const f16x4*)(&p_lds[row][c0]);
      const float inv = inv_l[row];
      f32x4 av;
      for (int j = 0; j < 4; ++j) av[j] = (float)pv[j] * inv;
      *(f32x4*)(outA + ((size_t)b * S_ + q0 + row) * S_ + c0) = av;
    }
  }

  // ---- O writeback: row = h*16 + 4*lg + r, col = d0v + lr ----
  for (int h = 0; h < 2; ++h)
    for (int r = 0; r < 4; ++r) {
      const int row = h * 16 + lg * 4 + r;
      const float ov = (h ? o1[r] : o0[r]) * inv_l[row];
      outO[((size_t)b * S_ + q0 + row) * D_ + d0v + lr] = ov;
    }
}

extern "C" void kernel_launch(void* const* d_in, const int* in_sizes, int n_in,
                              void* d_out, int out_size, void* d_ws, size_t ws_size,
                              hipStream_t stream) {
  const float* Q = (const float*)d_in[0];
  const float* K = (const float*)d_in[1];
  const float* V = (const float*)d_in[2];
  float* outO = (float*)d_out;
  float* outA = outO + (size_t)B_ * S_ * D_;

  const size_t NE = (size_t)B_ * S_ * D_;           // 4,194,304 per tensor
  const size_t need = 3 * NE * sizeof(_Float16);    // 24 MiB

  const int nblk = B_ * S_ / M_;  // 1024

  if (ws_size >= need) {
    _Float16* Qh = (_Float16*)d_ws;
    _Float16* Kh = Qh + NE;
    _Float16* Vt = Kh + NE;
    cvt_f16_kernel<<<2048, 256, 0, stream>>>(Q, Qh, (int)(NE / 4));
    cvt_f16_kernel<<<2048, 256, 0, stream>>>(K, Kh, (int)(NE / 4));
    trans_v_kernel<<<4096, 256, 0, stream>>>(V, Vt);
    attn_fused<true><<<nblk, 512, 0, stream>>>(nullptr, nullptr, nullptr,
                                               Qh, Kh, Vt, outO, outA);
  } else {
    attn_fused<false><<<nblk, 512, 0, stream>>>(Q, K, V,
                                                nullptr, nullptr, nullptr,
                                                outO, outA);
  }
}